// Round 2
// baseline (157.341 us; speedup 1.0000x reference)
//
#include <hip/hip_runtime.h>
#include <cstdint>
#include <cstddef>

#define NAGENT 64
#define WAVES_PER_BLOCK 4

// ---------------------------------------------------------------------------
// Kernel 1: fused. For i < xtotal: x = concat([obs, init], -1) elementwise,
// and the r==0/1 threads also write the compact xy[] array to ws.
// For i >= xtotal: fill the entire edge-index output region with -1.0f
// (emit overwrites the first E slots later in the stream).
// ---------------------------------------------------------------------------
__global__ __launch_bounds__(256) void concat_fill_kernel(
    const float* __restrict__ obs, const float* __restrict__ ego,
    const float* __restrict__ oth, float* __restrict__ out,
    float* __restrict__ xy, int xtotal, int total)
{
    int i = blockIdx.x * blockDim.x + threadIdx.x;
    if (i >= total) return;
    if (i < xtotal) {
        unsigned int ui = (unsigned int)i;
        unsigned int q = ui / 18u;          // row = b*64 + n
        unsigned int r = ui - q * 18u;      // col
        float v;
        if (r < 16u) {
            v = obs[(size_t)q * 16u + r];
            if (r < 2u) xy[2u * q + r] = v;  // compact (x,y) for edge build
        } else {
            const float* ini = ((q & 63u) == 0u) ? ego : oth;
            v = ini[r - 16u];
        }
        out[i] = v;
    } else {
        out[i] = -1.0f;   // pad default for both edge rows
    }
}

// ---------------------------------------------------------------------------
// Kernel 2: per-batch edge construction. One wave (64 lanes) per batch.
// Builds a 64x64 adjacency bitmask in LDS (dedupe + lexsort for free),
// writes the 2-word-per-row bitmask + per-batch count to workspace.
// ---------------------------------------------------------------------------
__global__ __launch_bounds__(64 * WAVES_PER_BLOCK) void build_edges_kernel(
    const float* __restrict__ xy, unsigned int* __restrict__ adj_g,
    int* __restrict__ counts, int B)
{
    const int wave = threadIdx.x >> 6;
    const int lane = threadIdx.x & 63;
    const int b = blockIdx.x * WAVES_PER_BLOCK + wave;
    if (blockIdx.x * WAVES_PER_BLOCK >= B) return;   // whole-block guard

    __shared__ int   order_s[WAVES_PER_BLOCK][NAGENT];
    __shared__ float ys_s[WAVES_PER_BLOCK][NAGENT];
    __shared__ unsigned int adj_s[WAVES_PER_BLOCK][NAGENT][2];

    const float2 p = ((const float2*)xy)[(size_t)b * NAGENT + lane];
    const float x = p.x;
    const float y = p.y;

    // Stable rank by x (tie-break: original index) — all-pairs via shfl
    int rank = 0;
    #pragma unroll 8
    for (int j = 0; j < 64; ++j) {
        float xj = __shfl(x, j);
        rank += (xj < x || (xj == x && j < lane)) ? 1 : 0;
    }
    order_s[wave][rank] = lane;   // sorted position -> agent id
    ys_s[wave][lane] = y;
    adj_s[wave][lane][0] = 0u;
    adj_s[wave][lane][1] = 0u;
    __syncthreads();

    // Lane = sorted position. Compute the 5 lane-band masks for that agent.
    const int a = order_s[wave][lane];
    const float ya = ys_s[wave][a];
    const float T1 = 1.0f / 3.0f;   // 0x3EAAAAAB == f32(1/3) in the reference
    const float T2 = 2.0f / 3.0f;   // 0x3F2AAAAB == f32(2/3)
    const bool m0 = (ya <= T1) && (ya > 0.0f);
    const bool m1 = (ya > T1) && (ya <= T2);
    const bool m2 = (ya >= T2) && (ya < 1.0f);
    bool ms[5];
    ms[0] = m0; ms[1] = m1; ms[2] = m2; ms[3] = m0 || m1; ms[4] = m1 || m2;

    // For each mask: connect consecutive members (in x order) bidirectionally.
    #pragma unroll
    for (int k = 0; k < 5; ++k) {
        unsigned long long bits = __ballot(ms[k]);
        unsigned long long higher = (lane == 63) ? 0ULL : (bits >> (lane + 1));
        if (ms[k] && higher != 0ULL) {
            int q = lane + 1 + __builtin_ctzll(higher);   // next member position
            int bb = order_s[wave][q];
            atomicOr(&adj_s[wave][a][bb >> 5], 1u << (bb & 31));
            atomicOr(&adj_s[wave][bb][a >> 5], 1u << (a & 31));
        }
    }
    __syncthreads();

    const unsigned int r0 = adj_s[wave][lane][0];
    const unsigned int r1 = adj_s[wave][lane][1];
    adj_g[(size_t)b * 128 + 2 * lane + 0] = r0;
    adj_g[(size_t)b * 128 + 2 * lane + 1] = r1;

    // Wave-reduce total bit count for this batch
    int c = __popc(r0) + __popc(r1);
    #pragma unroll
    for (int off = 1; off < 64; off <<= 1) {
        int t = __shfl_up(c, off);
        if (lane >= off) c += t;
    }
    if (lane == 63) counts[b] = c;
}

// ---------------------------------------------------------------------------
// Kernel 3: exclusive prefix sum of per-batch counts (single block).
// ---------------------------------------------------------------------------
__global__ __launch_bounds__(256) void scan_kernel(
    const int* __restrict__ counts, int* __restrict__ offsets, int B)
{
    __shared__ int part[256];
    const int t = threadIdx.x;
    const int per = (B + 255) / 256;
    const int beg = t * per;
    int s = 0;
    for (int i = 0; i < per; ++i) { int k = beg + i; if (k < B) s += counts[k]; }
    part[t] = s;
    __syncthreads();
    for (int off = 1; off < 256; off <<= 1) {
        int v = (t >= off) ? part[t - off] : 0;
        __syncthreads();
        part[t] += v;
        __syncthreads();
    }
    int run = part[t] - s;   // exclusive base for this thread's chunk
    for (int i = 0; i < per; ++i) {
        int k = beg + i;
        if (k < B) { offsets[k] = run; run += counts[k]; }
    }
}

// ---------------------------------------------------------------------------
// Kernel 4: per-batch bit enumeration -> float edge indices at offsets[b].
// Row-major bit order == (src,dst)-lexicographic == global lexsort order.
// ---------------------------------------------------------------------------
__global__ __launch_bounds__(64) void emit_kernel(
    const unsigned int* __restrict__ adj_g, const int* __restrict__ offsets,
    float* __restrict__ out_es, float* __restrict__ out_ed)
{
    const int b = blockIdx.x;
    const int lane = threadIdx.x;
    unsigned int r0 = adj_g[(size_t)b * 128 + 2 * lane + 0];
    unsigned int r1 = adj_g[(size_t)b * 128 + 2 * lane + 1];
    const int c = __popc(r0) + __popc(r1);

    // Inclusive wave prefix sum -> row start within batch
    int pre = c;
    #pragma unroll
    for (int off = 1; off < 64; off <<= 1) {
        int t = __shfl_up(pre, off);
        if (lane >= off) pre += t;
    }
    int idx = offsets[b] + pre - c;
    const int gbase = b * NAGENT;
    const float sg = (float)(gbase + lane);
    while (r0) {
        int d = __builtin_ctz(r0); r0 &= r0 - 1u;
        out_es[idx] = sg; out_ed[idx] = (float)(gbase + d); ++idx;
    }
    while (r1) {
        int d = 32 + __builtin_ctz(r1); r1 &= r1 - 1u;
        out_es[idx] = sg; out_ed[idx] = (float)(gbase + d); ++idx;
    }
}

// ---------------------------------------------------------------------------
extern "C" void kernel_launch(void* const* d_in, const int* in_sizes, int n_in,
                              void* d_out, int out_size, void* d_ws, size_t ws_size,
                              hipStream_t stream)
{
    const float* obs = (const float*)d_in[0];
    const float* ego = (const float*)d_in[1];
    const float* oth = (const float*)d_in[2];

    const int B = in_sizes[0] / (NAGENT * 16);        // 8192
    const int M = B * NAGENT;                          // 524288
    const int xtotal = M * 18;                         // 9437184
    const int slots = B * 10 * (NAGENT - 1);           // 5160960
    const int total = xtotal + 2 * slots;              // == out_size

    float* out_x  = (float*)d_out;
    float* out_es = out_x + xtotal;
    float* out_ed = out_es + slots;

    // Workspace (floats/ints): xy[2*M] | adj[B*128 u32] | counts[B] | offsets[B]
    float*        xy      = (float*)d_ws;
    unsigned int* adj_g   = (unsigned int*)(xy + (size_t)2 * M);
    int*          counts  = (int*)(adj_g + (size_t)B * 128);
    int*          offsets = counts + B;

    concat_fill_kernel<<<(total + 255) / 256, 256, 0, stream>>>(
        obs, ego, oth, (float*)d_out, xy, xtotal, total);
    build_edges_kernel<<<(B + WAVES_PER_BLOCK - 1) / WAVES_PER_BLOCK,
                         64 * WAVES_PER_BLOCK, 0, stream>>>(xy, adj_g, counts, B);
    scan_kernel<<<1, 256, 0, stream>>>(counts, offsets, B);
    emit_kernel<<<B, 64, 0, stream>>>(adj_g, offsets, out_es, out_ed);
}